// Round 2
// baseline (680.762 us; speedup 1.0000x reference)
//
#include <hip/hip_runtime.h>
#include <hip/hip_bf16.h>
#include <stdint.h>

#define BDIM 512
#define CDIM 200000
#define DDIM 256
#define S_SC 30.0f
#define MARG 0.2f

#define BN 128
#define NBLK 1563      // ceil(200000/128)
#define NBLK_PAD 1568

typedef float f4 __attribute__((ext_vector_type(4)));
typedef float f32x4 __attribute__((ext_vector_type(4)));
typedef short bf16x8 __attribute__((ext_vector_type(8)));
typedef unsigned short u16x4 __attribute__((ext_vector_type(4)));

__device__ __forceinline__ unsigned short f2bf(float f) {
  unsigned int u = __float_as_uint(f);
  u += 0x7FFF + ((u >> 16) & 1);   // RNE
  return (unsigned short)(u >> 16);
}

__device__ __forceinline__ float wave_allsum(float v) {
#pragma unroll
  for (int off = 32; off >= 1; off >>= 1) v += __shfl_xor(v, off);
  return v;
}

// ---------------- kernel 1: normalize x rows -> bf16 ----------------
__global__ __launch_bounds__(256) void k_xnorm(const float* __restrict__ x,
                                               unsigned short* __restrict__ xn) {
  const int lane = threadIdx.x & 63;
  const int wv = threadIdx.x >> 6;
  const int row = blockIdx.x * 4 + wv;          // 128 blocks * 4 waves = 512 rows
  f4 v = *(const f4*)(x + (size_t)row * DDIM + lane * 4);
  float ssq = v[0]*v[0] + v[1]*v[1] + v[2]*v[2] + v[3]*v[3];
  ssq = wave_allsum(ssq);
  const float scale = 1.0f / fmaxf(sqrtf(ssq), 1e-12f);
  u16x4 o;
  o[0] = f2bf(v[0]*scale); o[1] = f2bf(v[1]*scale);
  o[2] = f2bf(v[2]*scale); o[3] = f2bf(v[3]*scale);
  *(u16x4*)(xn + (size_t)row * DDIM + lane * 4) = o;
}

// ---------------- kernel 2: fused normalize(w) + bf16 MFMA GEMM + exp-sum ----
// Dominant dispatch: reads w (205 MB) exactly once; designed for HBM roofline.
__global__ __launch_bounds__(512) void k_gemm(const float* __restrict__ w,
                                              const unsigned short* __restrict__ xn,
                                              float* __restrict__ partial_t) {
  __shared__ union {
    char wb[BN * 512];        // 128 rows x 256 bf16 (512 B/row), XOR-swizzled
    float scratch[8][BDIM];   // reused after A-frags are hoisted (16 KB)
  } sm;
  const int tid = threadIdx.x;
  const int lane = tid & 63;
  const int wv = tid >> 6;                 // 8 waves
  const int c0 = blockIdx.x * BN;

  // ---- stage + normalize 16 w-rows per wave: fp32 HBM -> bf16 LDS ----
  for (int rr = 0; rr < 16; ++rr) {
    const int row = wv * 16 + rr;
    const int cg = c0 + row;
    f4 v = {0.f, 0.f, 0.f, 0.f};
    if (cg < CDIM) v = *(const f4*)(w + (size_t)cg * DDIM + lane * 4);
    float ssq = v[0]*v[0] + v[1]*v[1] + v[2]*v[2] + v[3]*v[3];
    ssq = wave_allsum(ssq);
    const float scale = 1.0f / fmaxf(sqrtf(ssq), 1e-12f);  // zero row -> wn stays 0
    u16x4 o;
    o[0] = f2bf(v[0]*scale); o[1] = f2bf(v[1]*scale);
    o[2] = f2bf(v[2]*scale); o[3] = f2bf(v[3]*scale);
    const int byte = (row * 512 + lane * 8) ^ ((row & 7) << 4);  // T2 swizzle
    *(u16x4*)(sm.wb + byte) = o;
  }
  __syncthreads();

  // ---- hoist all A fragments (this wave's 16 classes x K=256) into regs ----
  bf16x8 afrag[8];
  const int arow = wv * 16 + (lane & 15);
  const int asw = (arow & 7) << 4;
  #pragma unroll
  for (int kk = 0; kk < 8; ++kk) {
    const int byte = (arow * 512 + kk * 64 + (lane >> 4) * 16) ^ asw;
    afrag[kk] = *(const bf16x8*)(sm.wb + byte);   // ds_read_b128, <=2-way (free)
  }
  __syncthreads();   // after this, sm.wb is dead -> scratch alias is safe

  // ---- main loop: 32 b-tiles of 16 batch rows, K=256 via 8 MFMAs ----
  const unsigned short* xbase = xn + (size_t)(lane & 15) * DDIM + (lane >> 4) * 8;
  #pragma unroll 4
  for (int bt = 0; bt < 32; ++bt) {
    const unsigned short* xb = xbase + bt * 16 * DDIM;
    f32x4 acc = {0.f, 0.f, 0.f, 0.f};
    #pragma unroll
    for (int kk = 0; kk < 8; ++kk) {
      bf16x8 bfrag = *(const bf16x8*)(xb + kk * 32);  // 16B global, L1-hot
      acc = __builtin_amdgcn_mfma_f32_16x16x32_bf16(afrag[kk], bfrag, acc, 0, 0, 0);
    }
    // D layout (m89-verified): col(batch) = lane&15, row(class) = (lane>>4)*4+q
    float e = 0.f;
    #pragma unroll
    for (int q = 0; q < 4; ++q) {
      const int cg = c0 + wv * 16 + (lane >> 4) * 4 + q;
      const float ex = __expf(S_SC * acc[q]);   // logits <= 30 -> no overflow
      e += (cg < CDIM) ? ex : 0.f;
    }
    e += __shfl_xor(e, 16);
    e += __shfl_xor(e, 32);
    if (lane < 16) sm.scratch[wv][bt * 16 + lane] = e;  // wave-private row
  }
  __syncthreads();

  // ---- combine 8 waves, write per-block partial (transposed, coalesced later) ----
  float s = 0.f;
  #pragma unroll
  for (int i = 0; i < 8; ++i) s += sm.scratch[i][tid];
  partial_t[(size_t)tid * NBLK_PAD + blockIdx.x] = s;
}

// ---------------- kernel 3: per-row reduce + fp32 target cosine + NLL ----------
__global__ __launch_bounds__(256) void k_row(const float* __restrict__ partial_t,
                                             const float* __restrict__ x,
                                             const float* __restrict__ w,
                                             const int* __restrict__ tg,
                                             float* __restrict__ nll) {
  const int b = blockIdx.x;
  const int tid = threadIdx.x;
  const int lane = tid & 63;
  const int wv = tid >> 6;
  __shared__ float s4[4];
  __shared__ float sct;

  // sumexp reduction over 1563 block-partials (coalesced: transposed layout)
  const float* p = partial_t + (size_t)b * NBLK_PAD;
  float s = 0.f;
  for (int r = tid; r < NBLK; r += 256) s += p[r];
  s = wave_allsum(s);
  if (lane == 0) s4[wv] = s;

  // fp32 target cosine (wave 0 only)
  if (wv == 0) {
    const int t = tg[b];
    f4 xv = *(const f4*)(x + (size_t)b * DDIM + lane * 4);
    f4 wv4 = *(const f4*)(w + (size_t)t * DDIM + lane * 4);
    float sx = xv[0]*xv[0] + xv[1]*xv[1] + xv[2]*xv[2] + xv[3]*xv[3];
    float sw = wv4[0]*wv4[0] + wv4[1]*wv4[1] + wv4[2]*wv4[2] + wv4[3]*wv4[3];
    float sd = xv[0]*wv4[0] + xv[1]*wv4[1] + xv[2]*wv4[2] + xv[3]*wv4[3];
    sx = wave_allsum(sx);
    sw = wave_allsum(sw);
    sd = wave_allsum(sd);
    if (lane == 0)
      sct = sd / (fmaxf(sqrtf(sx), 1e-12f) * fmaxf(sqrtf(sw), 1e-12f));
  }
  __syncthreads();

  if (tid == 0) {
    const float sumexp = s4[0] + s4[1] + s4[2] + s4[3];
    const float ct = sct;
    const float tl = S_SC * (ct - MARG);
    // swap unmodified target term for margin term
    const float adj = sumexp - __expf(S_SC * ct) + __expf(tl);
    nll[b] = logf(adj) - tl;
  }
}

// ---------------- kernel 4: mean over 512 rows ----------------
__global__ __launch_bounds__(512) void k_final(const float* __restrict__ nll,
                                               float* __restrict__ out) {
  const int tid = threadIdx.x;
  float v = nll[tid];
  v = wave_allsum(v);
  __shared__ float s8[8];
  if ((tid & 63) == 0) s8[tid >> 6] = v;
  __syncthreads();
  if (tid == 0) {
    float t = 0.f;
    #pragma unroll
    for (int i = 0; i < 8; ++i) t += s8[i];
    out[0] = t / (float)BDIM;
  }
}

extern "C" void kernel_launch(void* const* d_in, const int* in_sizes, int n_in,
                              void* d_out, int out_size, void* d_ws, size_t ws_size,
                              hipStream_t stream) {
  const float* x = (const float*)d_in[0];       // 512*256 fp32
  const float* w = (const float*)d_in[1];       // 200000*256 fp32
  const int* tg = (const int*)d_in[2];          // 512 int

  char* ws = (char*)d_ws;
  unsigned short* xn = (unsigned short*)ws;                          // 256 KiB
  float* partial_t = (float*)(ws + 262144);                          // 512*1568*4 B
  float* nll = (float*)(ws + 262144 + (size_t)BDIM * NBLK_PAD * 4);  // 512*4 B

  k_xnorm<<<128, 256, 0, stream>>>(x, xn);
  k_gemm<<<NBLK, 512, 0, stream>>>(w, xn, partial_t);
  k_row<<<BDIM, 256, 0, stream>>>(partial_t, x, w, tg, nll);
  k_final<<<1, 512, 0, stream>>>(nll, (float*)d_out);
}

// Round 3
// 332.551 us; speedup vs baseline: 2.0471x; 2.0471x over previous
//
#include <hip/hip_runtime.h>
#include <hip/hip_bf16.h>
#include <stdint.h>

#define BDIM 512
#define CDIM 200000
#define DDIM 256
#define S_SC 30.0f
#define MARG 0.2f

#define BN 128
#define NBLK 1563      // ceil(200000/128)
#define NBLK_PAD 1568

typedef float f4 __attribute__((ext_vector_type(4)));
typedef float f32x4 __attribute__((ext_vector_type(4)));
typedef short bf16x8 __attribute__((ext_vector_type(8)));
typedef unsigned short u16x4 __attribute__((ext_vector_type(4)));

__device__ __forceinline__ unsigned short f2bf(float f) {
  unsigned int u = __float_as_uint(f);
  u += 0x7FFF + ((u >> 16) & 1);   // RNE
  return (unsigned short)(u >> 16);
}

__device__ __forceinline__ float wave_allsum(float v) {
#pragma unroll
  for (int off = 32; off >= 1; off >>= 1) v += __shfl_xor(v, off);
  return v;
}

// ---- kernel 1: normalize x, emit MFMA-B-fragment-ordered bf16 buffer ----
// xn_frag layout: for (bt, kk, lane): 8 bf16 = xn[bt*16 + (lane&15)][kk*32 + (lane>>4)*8 + j]
// -> consumer's bfrag load is one contiguous 1KB per wave instruction.
__global__ __launch_bounds__(512) void k_xfrag(const float* __restrict__ x,
                                               unsigned short* __restrict__ xn_frag) {
  __shared__ float xtile[16][260];   // 260: bank-spread (4r+c), f4-aligned rows
  __shared__ float sscale[16];
  const int tid = threadIdx.x;
  const int lane = tid & 63;
  const int wv = tid >> 6;           // 8 waves
  const int bt = blockIdx.x;         // 32 blocks, 16 batch rows each

  // phase 1: each wave normalizes 2 rows
  #pragma unroll
  for (int h = 0; h < 2; ++h) {
    const int r = wv * 2 + h;
    f4 v = *(const f4*)(x + (size_t)(bt * 16 + r) * DDIM + lane * 4);
    float ssq = v[0]*v[0] + v[1]*v[1] + v[2]*v[2] + v[3]*v[3];
    ssq = wave_allsum(ssq);
    if (lane == 0) sscale[r] = 1.0f / fmaxf(sqrtf(ssq), 1e-12f);
    *(f4*)&xtile[r][lane * 4] = v;
  }
  __syncthreads();

  // phase 2: wave wv emits kk = wv fragment chunk (1KB contiguous store)
  const int kk = wv;
  const int r = lane & 15;
  const int c0f = kk * 32 + (lane >> 4) * 8;
  const float sc = sscale[r];
  f4 a = *(const f4*)&xtile[r][c0f];
  f4 b = *(const f4*)&xtile[r][c0f + 4];
  bf16x8 o;
  o[0] = (short)f2bf(a[0]*sc); o[1] = (short)f2bf(a[1]*sc);
  o[2] = (short)f2bf(a[2]*sc); o[3] = (short)f2bf(a[3]*sc);
  o[4] = (short)f2bf(b[0]*sc); o[5] = (short)f2bf(b[1]*sc);
  o[6] = (short)f2bf(b[2]*sc); o[7] = (short)f2bf(b[3]*sc);
  *(bf16x8*)(xn_frag + ((size_t)(bt * 8 + kk) * 64 + lane) * 8) = o;
}

// ---- kernel 2: fused normalize(w) + bf16 MFMA + exp-sum over 128 classes ----
// Each wave owns 4 batch-tiles (B in regs), streams 128 classes from LDS.
__global__ __launch_bounds__(512, 4) void k_gemm(const float* __restrict__ w,
                                                 const unsigned short* __restrict__ xn_frag,
                                                 float* __restrict__ partial_t) {
  __shared__ char wb[BN * 512];      // 128 class rows x 512B bf16, XOR-swizzled
  const int tid = threadIdx.x;
  const int lane = tid & 63;
  const int wv = tid >> 6;           // 8 waves
  const int c0 = blockIdx.x * BN;

  // ---- stage: 16 w-rows per wave, loads hoisted, butterflies interleaved ----
  f4 v[16];
  #pragma unroll
  for (int rr = 0; rr < 16; ++rr) {
    const int cg = c0 + wv * 16 + rr;
    f4 z = {0.f, 0.f, 0.f, 0.f};
    v[rr] = (cg < CDIM) ? *(const f4*)(w + (size_t)cg * DDIM + lane * 4) : z;
  }
  float ss[16];
  #pragma unroll
  for (int rr = 0; rr < 16; ++rr)
    ss[rr] = v[rr][0]*v[rr][0] + v[rr][1]*v[rr][1] + v[rr][2]*v[rr][2] + v[rr][3]*v[rr][3];
  #pragma unroll
  for (int off = 32; off >= 1; off >>= 1) {   // 16 independent chains interleave
    #pragma unroll
    for (int rr = 0; rr < 16; ++rr) ss[rr] += __shfl_xor(ss[rr], off);
  }
  #pragma unroll
  for (int rr = 0; rr < 16; ++rr) {
    const int row = wv * 16 + rr;
    const float sc = 1.0f / fmaxf(sqrtf(ss[rr]), 1e-12f);
    u16x4 o;
    o[0] = f2bf(v[rr][0]*sc); o[1] = f2bf(v[rr][1]*sc);
    o[2] = f2bf(v[rr][2]*sc); o[3] = f2bf(v[rr][3]*sc);
    const int byte = (row * 512 + lane * 8) ^ ((row & 7) << 4);  // T2 swizzle
    *(u16x4*)(wb + byte) = o;
  }
  __syncthreads();

  // ---- main: 2 passes x 2 batch-tiles in regs; stream classes from LDS ----
  #pragma unroll 1
  for (int o2 = 0; o2 < 2; ++o2) {
    bf16x8 bf[2][8];                 // 64 VGPRs: this wave's B fragments
    #pragma unroll
    for (int bt2 = 0; bt2 < 2; ++bt2) {
      const int bt = wv * 4 + o2 * 2 + bt2;
      #pragma unroll
      for (int kkk = 0; kkk < 8; ++kkk)
        bf[bt2][kkk] = *(const bf16x8*)(xn_frag + ((size_t)(bt * 8 + kkk) * 64 + lane) * 8);
    }
    float e0 = 0.f, e1 = 0.f;
    #pragma unroll 1
    for (int cf = 0; cf < 8; ++cf) {
      bf16x8 af[8];
      const int arow = cf * 16 + (lane & 15);
      const int asw = (arow & 7) << 4;
      #pragma unroll
      for (int kkk = 0; kkk < 8; ++kkk) {
        const int byte = (arow * 512 + kkk * 64 + (lane >> 4) * 16) ^ asw;
        af[kkk] = *(const bf16x8*)(wb + byte);   // ds_read_b128, <=2-way
      }
      f32x4 a0 = {0.f,0.f,0.f,0.f}, a1 = {0.f,0.f,0.f,0.f};
      #pragma unroll
      for (int kkk = 0; kkk < 8; ++kkk) {
        a0 = __builtin_amdgcn_mfma_f32_16x16x32_bf16(af[kkk], bf[0][kkk], a0, 0, 0, 0);
        a1 = __builtin_amdgcn_mfma_f32_16x16x32_bf16(af[kkk], bf[1][kkk], a1, 0, 0, 0);
      }
      // D: col(batch) = lane&15, row(class) = (lane>>4)*4 + q
      #pragma unroll
      for (int q = 0; q < 4; ++q) {
        const int cls = c0 + cf * 16 + (lane >> 4) * 4 + q;
        const bool ok = (cls < CDIM);
        e0 += ok ? __expf(S_SC * a0[q]) : 0.f;
        e1 += ok ? __expf(S_SC * a1[q]) : 0.f;
      }
    }
    // reduce over the 4 class-row groups (lane>>4); lanes 0-15 hold batch cols
    e0 += __shfl_xor(e0, 16); e0 += __shfl_xor(e0, 32);
    e1 += __shfl_xor(e1, 16); e1 += __shfl_xor(e1, 32);
    const int bt0 = wv * 4 + o2 * 2;
    if (lane < 16) {
      partial_t[(size_t)(bt0 * 16 + lane) * NBLK_PAD + blockIdx.x] = e0;
      partial_t[(size_t)((bt0 + 1) * 16 + lane) * NBLK_PAD + blockIdx.x] = e1;
    }
  }
}

// ---- kernel 3: per-row reduce + fp32 target cosine + NLL ----
__global__ __launch_bounds__(256) void k_row(const float* __restrict__ partial_t,
                                             const float* __restrict__ x,
                                             const float* __restrict__ w,
                                             const int* __restrict__ tg,
                                             float* __restrict__ nll) {
  const int b = blockIdx.x;
  const int tid = threadIdx.x;
  const int lane = tid & 63;
  const int wv = tid >> 6;
  __shared__ float s4[4];
  __shared__ float sct;

  const float* p = partial_t + (size_t)b * NBLK_PAD;
  float s = 0.f;
  for (int r = tid; r < NBLK; r += 256) s += p[r];   // coalesced
  s = wave_allsum(s);
  if (lane == 0) s4[wv] = s;

  if (wv == 0) {   // fp32 target cosine
    const int t = tg[b];
    f4 xv = *(const f4*)(x + (size_t)b * DDIM + lane * 4);
    f4 wv4 = *(const f4*)(w + (size_t)t * DDIM + lane * 4);
    float sx = xv[0]*xv[0] + xv[1]*xv[1] + xv[2]*xv[2] + xv[3]*xv[3];
    float sw = wv4[0]*wv4[0] + wv4[1]*wv4[1] + wv4[2]*wv4[2] + wv4[3]*wv4[3];
    float sd = xv[0]*wv4[0] + xv[1]*wv4[1] + xv[2]*wv4[2] + xv[3]*wv4[3];
    sx = wave_allsum(sx);
    sw = wave_allsum(sw);
    sd = wave_allsum(sd);
    if (lane == 0)
      sct = sd / (fmaxf(sqrtf(sx), 1e-12f) * fmaxf(sqrtf(sw), 1e-12f));
  }
  __syncthreads();

  if (tid == 0) {
    const float sumexp = s4[0] + s4[1] + s4[2] + s4[3];
    const float ct = sct;
    const float tl = S_SC * (ct - MARG);
    const float adj = sumexp - __expf(S_SC * ct) + __expf(tl);
    nll[b] = logf(adj) - tl;
  }
}

// ---- kernel 4: mean over 512 rows ----
__global__ __launch_bounds__(512) void k_final(const float* __restrict__ nll,
                                               float* __restrict__ out) {
  const int tid = threadIdx.x;
  float v = nll[tid];
  v = wave_allsum(v);
  __shared__ float s8[8];
  if ((tid & 63) == 0) s8[tid >> 6] = v;
  __syncthreads();
  if (tid == 0) {
    float t = 0.f;
    #pragma unroll
    for (int i = 0; i < 8; ++i) t += s8[i];
    out[0] = t / (float)BDIM;
  }
}

extern "C" void kernel_launch(void* const* d_in, const int* in_sizes, int n_in,
                              void* d_out, int out_size, void* d_ws, size_t ws_size,
                              hipStream_t stream) {
  const float* x = (const float*)d_in[0];       // 512*256 fp32
  const float* w = (const float*)d_in[1];       // 200000*256 fp32
  const int* tg = (const int*)d_in[2];          // 512 int

  char* ws = (char*)d_ws;
  unsigned short* xn_frag = (unsigned short*)ws;                     // 256 KiB
  float* partial_t = (float*)(ws + 262144);                          // 512*1568*4 B
  float* nll = (float*)(ws + 262144 + (size_t)BDIM * NBLK_PAD * 4);  // 2 KiB

  k_xfrag<<<32, 512, 0, stream>>>(x, xn_frag);
  k_gemm<<<NBLK, 512, 0, stream>>>(w, xn_frag, partial_t);
  k_row<<<BDIM, 256, 0, stream>>>(partial_t, x, w, tg, nll);
  k_final<<<1, 512, 0, stream>>>(nll, (float*)d_out);
}